// Round 13
// baseline (304.328 us; speedup 1.0000x reference)
//
#include <hip/hip_runtime.h>
#include <hip/hip_bf16.h>
#include <hip/hip_cooperative_groups.h>

namespace cg = cooperative_groups;

#define N_NODE 100000
#define N_NET  20000
#define NE     200000
#define H_NODE 64
#define H_NET  32
#define H_PIN  16
#define O_NODE 32
#define O_NET  64
#define CSR_STRIDE 64   // max net degree ~26 for this input (Binomial(2e5,1/2e4))

#define ZNPB 16

// ---------------- workspace layout (bytes, 16-aligned) ----------------
// zeroed by memset: [0, 480000)
//   node_deg : int  [N_NODE]          off 0          (400000)
//   net_cnt  : int  [N_NET]           off 400000     (80000)
// csr : int2  [N_NET*64]              off 480000     (10240000)
// Zb  : bf16  [N_NET*512] [n][o][k]   off 10720000   (20480000)
// C   : float [N_NET*32]              off 31200000   (2560000)

#define OFF_NETCNT  400000
#define OFF_CSR     480000
#define OFF_Z       10720000
#define OFF_C       31200000
#define ZERO_BYTES  480000

static __device__ __forceinline__ unsigned short f2bf(float f) {
    unsigned int u = __float_as_uint(f);
    u += 0x7fff + ((u >> 16) & 1);          // round-to-nearest-even
    return (unsigned short)(u >> 16);
}
static __device__ __forceinline__ float bf2f(unsigned short h) {
    return __uint_as_float(((unsigned int)h) << 16);
}

// ---------------- phase bodies (shared by coop and split paths) ----------------

static __device__ __forceinline__ void zc_body(int vb, int t,
        const float* __restrict__ net_feat, const float* __restrict__ W2,
        const float* __restrict__ b2, unsigned short* __restrict__ Zb,
        float* __restrict__ C, float sy[ZNPB][H_NET]) {
    int base = vb * ZNPB;
    for (int idx = t; idx < ZNPB * H_NET; idx += 256)
        sy[idx >> 5][idx & 31] = net_feat[(base + (idx >> 5)) * H_NET + (idx & 31)];
    __syncthreads();
    int o = t & 31, k4 = (t >> 5) & 3, rep = t >> 7;   // 8 nets per thread
    const float* w2p = W2 + (k4 * 4) * 1024 + o;
    float4 acc[8];
#pragma unroll
    for (int g = 0; g < 8; g++) acc[g] = make_float4(0.f, 0.f, 0.f, 0.f);
#pragma unroll 4
    for (int i = 0; i < H_NET; i++) {
        float w0 = w2p[0 * 1024 + i * 32];
        float w1 = w2p[1 * 1024 + i * 32];
        float w2v = w2p[2 * 1024 + i * 32];
        float w3 = w2p[3 * 1024 + i * 32];
#pragma unroll
        for (int g = 0; g < 8; g++) {
            float y = sy[rep * 8 + g][i];
            acc[g].x += w0 * y; acc[g].y += w1 * y;
            acc[g].z += w2v * y; acc[g].w += w3 * y;
        }
    }
#pragma unroll
    for (int g = 0; g < 8; g++) {
        int n = base + rep * 8 + g;
        ushort4 uz;
        uz.x = f2bf(acc[g].x); uz.y = f2bf(acc[g].y);
        uz.z = f2bf(acc[g].z); uz.w = f2bf(acc[g].w);
        *(ushort4*)&Zb[(size_t)n * 512 + o * 16 + k4 * 4] = uz;
    }
#pragma unroll
    for (int r = 0; r < 2; r++) {
        int idx = t + r * 256;
        int g = idx >> 5, oo = idx & 31;
        float a = 0.f;
#pragma unroll
        for (int i = 0; i < H_NET; i++) a += sy[g][i] * b2[i * 32 + oo];
        C[(base + g) * 32 + oo] = a;
    }
}

// per-net body: one wave, net n. RULE (gfx950): every __shfl executes as an
// UNCONDITIONAL statement with the full wave converged — never inside a
// ternary/if with a LANE-VARYING condition. Select on the RESULT.
static __device__ __forceinline__ void net_body(int n, int w, int l,
        const float* __restrict__ node_feat, const int* __restrict__ node_deg,
        const int* __restrict__ net_cnt, const int2* __restrict__ csr,
        const float* __restrict__ W1, const float* __restrict__ b1,
        const unsigned short* __restrict__ Zb, const float* __restrict__ Cg,
        const float* __restrict__ pin_feat,
        float* __restrict__ out_net, float* __restrict__ out_node,
        float spin[4][32][16], float4 srow4[4][16]) {
    int beg = n * CSR_STRIDE, deg = net_cnt[n];
    int o = l & 31, half = l >> 5, q = l >> 4, f = l & 15;

    float z[16];
    {
        const uint4* zp = (const uint4*)&Zb[(size_t)n * 512 + o * 16];
        uint4 za = zp[0], zb = zp[1];
        unsigned int uu[8] = {za.x, za.y, za.z, za.w, zb.x, zb.y, zb.z, zb.w};
#pragma unroll
        for (int i = 0; i < 8; i++) {
            z[2 * i]     = bf2f((unsigned short)(uu[i] & 0xffffu));
            z[2 * i + 1] = bf2f((unsigned short)(uu[i] >> 16));
        }
    }
    float c = Cg[n * 32 + o];
    const float4* nf4 = (const float4*)node_feat;
    const float4* pf4 = (const float4*)pin_feat;
    float4 acc4 = make_float4(0.f, 0.f, 0.f, 0.f);

    for (int j0 = 0; j0 < deg; j0 += 32) {
        int cnt = deg - j0; if (cnt > 32) cnt = 32;    // wave-uniform
        int vj = 0, ej = 0; float sj = 0.f;
        if (l < cnt) {
            int2 ev = csr[beg + j0 + l];
            ej = ev.x; vj = ev.y;
            float dv = (float)node_deg[vj]; if (dv < 1.f) dv = 1.f;
            sj = rsqrtf(dv);
        }
        {   // stage pins to LDS, edges 0..15
            int jj = l >> 2;
            int src = (jj < cnt) ? jj : cnt - 1;
            int e = __shfl(ej, src);
            float4 pv = pf4[(size_t)e * 4 + (l & 3)];
            ((float4*)&spin[w][jj][0])[l & 3] = pv;
        }
        if (cnt > 16) {   // wave-uniform branch
            int jj = 16 + (l >> 2);
            int src = (jj < cnt) ? jj : cnt - 1;
            int e = __shfl(ej, src);
            float4 pv = pf4[(size_t)e * 4 + (l & 3)];
            ((float4*)&spin[w][jj][0])[l & 3] = pv;
        }
        {   // gather node rows, edges 0..15
            int vv[4]; float ss[4];
#pragma unroll
            for (int r = 0; r < 4; r++) {
                int jj = r * 4 + q;
                int src = (jj < cnt) ? jj : cnt - 1;
                vv[r] = __shfl(vj, src);
                float sv = __shfl(sj, src);
                ss[r] = (jj < cnt) ? sv : 0.f;
            }
            float4 xx[4];
#pragma unroll
            for (int r = 0; r < 4; r++) xx[r] = nf4[(size_t)vv[r] * 16 + f];
#pragma unroll
            for (int r = 0; r < 4; r++) {
                acc4.x += xx[r].x * ss[r]; acc4.y += xx[r].y * ss[r];
                acc4.z += xx[r].z * ss[r]; acc4.w += xx[r].w * ss[r];
            }
        }
        if (cnt > 16) {
            int vv[4]; float ss[4];
#pragma unroll
            for (int r = 0; r < 4; r++) {
                int jj = 16 + r * 4 + q;
                int src = (jj < cnt) ? jj : cnt - 1;
                vv[r] = __shfl(vj, src);
                float sv = __shfl(sj, src);
                ss[r] = (jj < cnt) ? sv : 0.f;
            }
            float4 xx[4];
#pragma unroll
            for (int r = 0; r < 4; r++) xx[r] = nf4[(size_t)vv[r] * 16 + f];
#pragma unroll
            for (int r = 0; r < 4; r++) {
                acc4.x += xx[r].x * ss[r]; acc4.y += xx[r].y * ss[r];
                acc4.z += xx[r].z * ss[r]; acc4.w += xx[r].w * ss[r];
            }
        }
        // messages: half-wave per edge; pins LDS; z regs; direct scatter
        for (int jj = 0; jj < cnt; jj += 2) {
            int je = jj + half;
            int src = (je < cnt) ? je : cnt - 1;
            int v = __shfl(vj, src);
            float sv = __shfl(sj, src);
            float inv = sv * sv;                       // 1/deg_v
            const float4* pr = (const float4*)&spin[w][src][0];
            float m = c;
#pragma unroll
            for (int k4 = 0; k4 < 4; k4++) {
                float4 pv = pr[k4];
                m += pv.x * z[k4 * 4 + 0] + pv.y * z[k4 * 4 + 1]
                   + pv.z * z[k4 * 4 + 2] + pv.w * z[k4 * 4 + 3];
            }
            if (je < cnt) atomicAdd(&out_node[(size_t)v * O_NODE + o], m * inv);
        }
    }
    acc4.x += __shfl_xor(acc4.x, 16); acc4.y += __shfl_xor(acc4.y, 16);
    acc4.z += __shfl_xor(acc4.z, 16); acc4.w += __shfl_xor(acc4.w, 16);
    acc4.x += __shfl_xor(acc4.x, 32); acc4.y += __shfl_xor(acc4.y, 32);
    acc4.z += __shfl_xor(acc4.z, 32); acc4.w += __shfl_xor(acc4.w, 32);
    float dn = (deg < 1) ? 1.f : (float)deg;
    float rs = rsqrtf(dn);
    if (l < 16)
        srow4[w][l] = make_float4(acc4.x * rs, acc4.y * rs, acc4.z * rs, acc4.w * rs);
    // srow4[w]/spin[w] are same-wave LDS: no __syncthreads needed
    {
        const float* a = (const float*)&srow4[w][0];
        float oacc = b1[l];
#pragma unroll 16
        for (int h = 0; h < H_NODE; h++) oacc += a[h] * W1[h * O_NET + l];
        out_net[n * O_NET + l] = oacc;
    }
}

// ---------------- split path (fallback, round-11 proven) ----------------
#define BLD_EDGE_BLKS 782
#define BLD_Z_BLKS    1250
#define BLD_INIT_BLKS 3125

__global__ void k_build(const int* __restrict__ en, const int* __restrict__ em,
                        int* __restrict__ node_deg, int* __restrict__ net_cnt,
                        int2* __restrict__ csr,
                        const float* __restrict__ net_feat,
                        const float* __restrict__ W2, const float* __restrict__ b2,
                        unsigned short* __restrict__ Zb, float* __restrict__ C,
                        const float* __restrict__ b_nn,
                        float* __restrict__ out_node) {
    int t = threadIdx.x, b = blockIdx.x;
    if (b < BLD_EDGE_BLKS) {
        int e = b * 256 + t;
        if (e < NE) {
            int v = en[e], n = em[e];
            atomicAdd(&node_deg[v], 1);
            int slot = atomicAdd(&net_cnt[n], 1);
            if (slot < CSR_STRIDE) csr[n * CSR_STRIDE + slot] = make_int2(e, v);
        }
        return;
    }
    if (b < BLD_EDGE_BLKS + BLD_Z_BLKS) {
        __shared__ float sy[ZNPB][H_NET];
        zc_body(b - BLD_EDGE_BLKS, t, net_feat, W2, b2, Zb, C, sy);
        return;
    }
    int idx = (b - BLD_EDGE_BLKS - BLD_Z_BLKS) * 256 + t;   // < 800000 float4s
    ((float4*)out_node)[idx] = ((const float4*)b_nn)[idx & 7];
}

__global__ void k_net(const float* __restrict__ node_feat,
                      const int* __restrict__ node_deg,
                      const int* __restrict__ net_cnt,
                      const int2* __restrict__ csr,
                      const float* __restrict__ W1, const float* __restrict__ b1,
                      const unsigned short* __restrict__ Zb,
                      const float* __restrict__ Cg,
                      const float* __restrict__ pin_feat,
                      float* __restrict__ out_net, float* __restrict__ out_node) {
    __shared__ float  spin[4][32][16];
    __shared__ float4 srow4[4][16];
    int t = threadIdx.x;
    int w = t >> 6, l = t & 63;
    int n = blockIdx.x * 4 + w;
    net_body(n, w, l, node_feat, node_deg, net_cnt, csr, W1, b1, Zb, Cg,
             pin_feat, out_net, out_node, spin, srow4);
}

// ---------------- cooperative path (all grid-stride) ----------------
__global__ __launch_bounds__(256, 4)
void k_all(const int* __restrict__ en, const int* __restrict__ em,
           int* __restrict__ node_deg, int* __restrict__ net_cnt,
           int2* __restrict__ csr,
           const float* __restrict__ node_feat,
           const float* __restrict__ net_feat,
           const float* __restrict__ pin_feat,
           const float* __restrict__ W1, const float* __restrict__ b1,
           const float* __restrict__ W2, const float* __restrict__ b2,
           const float* __restrict__ b_nn,
           unsigned short* __restrict__ Zb, float* __restrict__ C,
           float* __restrict__ out_net, float* __restrict__ out_node) {
    cg::grid_group grid = cg::this_grid();
    int t = threadIdx.x, b = blockIdx.x;
    int nb = gridDim.x;
    __shared__ float sy[ZNPB][H_NET];
    __shared__ float  spin[4][32][16];
    __shared__ float4 srow4[4][16];

    for (int e = b * 256 + t; e < NE; e += nb * 256) {
        int v = en[e], n = em[e];
        atomicAdd(&node_deg[v], 1);
        int slot = atomicAdd(&net_cnt[n], 1);
        if (slot < CSR_STRIDE) csr[n * CSR_STRIDE + slot] = make_int2(e, v);
    }
    for (int idx = b * 256 + t; idx < N_NODE * O_NODE / 4; idx += nb * 256)
        ((float4*)out_node)[idx] = ((const float4*)b_nn)[idx & 7];
    for (int vb = b; vb < N_NET / ZNPB; vb += nb) {
        __syncthreads();   // WAR on sy across iterations
        zc_body(vb, t, net_feat, W2, b2, Zb, C, sy);
    }

    grid.sync();

    int w = t >> 6, l = t & 63;
    for (int vb = b; vb < N_NET / 4; vb += nb) {
        net_body(vb * 4 + w, w, l, node_feat, node_deg, net_cnt, csr, W1, b1,
                 Zb, C, pin_feat, out_net, out_node, spin, srow4);
    }
}

extern "C" void kernel_launch(void* const* d_in, const int* in_sizes, int n_in,
                              void* d_out, int out_size, void* d_ws, size_t ws_size,
                              hipStream_t stream) {
    const float* node_feat = (const float*)d_in[0];
    const float* net_feat  = (const float*)d_in[1];
    const float* pin_feat  = (const float*)d_in[2];
    const int*   edge_node = (const int*)d_in[3];
    const int*   edge_net  = (const int*)d_in[4];
    const float* W1        = (const float*)d_in[5];
    const float* b1        = (const float*)d_in[6];
    const float* W2        = (const float*)d_in[7];
    const float* b2        = (const float*)d_in[8];
    const float* b_nn      = (const float*)d_in[9];

    float* out_node = (float*)d_out;                          // [N_NODE*32]
    float* out_net  = out_node + (size_t)N_NODE * O_NODE;     // [N_NET*64]

    char* ws = (char*)d_ws;
    int*            node_deg = (int*)ws;
    int*            net_cnt  = (int*)(ws + OFF_NETCNT);
    int2*           csr      = (int2*)(ws + OFF_CSR);
    unsigned short* Zb       = (unsigned short*)(ws + OFF_Z);
    float*          C        = (float*)(ws + OFF_C);

    (void)hipMemsetAsync(ws, 0, ZERO_BYTES, stream);

    // ---- gated cooperative attempt (queries are host-side, capture-safe) ----
    bool coop_done = false;
    int dev = 0;
    if (hipGetDevice(&dev) == hipSuccess) {
        int coopAttr = 0;
        (void)hipDeviceGetAttribute(&coopAttr, hipDeviceAttributeCooperativeLaunch, dev);
        int maxPerCU = 0;
        hipError_t qerr = hipOccupancyMaxActiveBlocksPerMultiprocessor(
            &maxPerCU, (const void*)k_all, 256, 0);
        if (coopAttr && qerr == hipSuccess && maxPerCU >= 1) {
            int nblk = maxPerCU * 256;
            if (nblk > 1024) nblk = 1024;
            void* args[] = {
                (void*)&edge_node, (void*)&edge_net,
                (void*)&node_deg, (void*)&net_cnt, (void*)&csr,
                (void*)&node_feat, (void*)&net_feat, (void*)&pin_feat,
                (void*)&W1, (void*)&b1, (void*)&W2, (void*)&b2, (void*)&b_nn,
                (void*)&Zb, (void*)&C, (void*)&out_net, (void*)&out_node,
            };
            hipError_t lerr = hipLaunchCooperativeKernel(
                (const void*)k_all, dim3(nblk), dim3(256), args, 0, stream);
            coop_done = (lerr == hipSuccess);
        }
    }

    if (!coop_done) {   // proven split path (round 11)
        k_build<<<BLD_EDGE_BLKS + BLD_Z_BLKS + BLD_INIT_BLKS, 256, 0, stream>>>(
            edge_node, edge_net, node_deg, net_cnt, csr,
            net_feat, W2, b2, Zb, C, b_nn, out_node);
        k_net<<<N_NET / 4, 256, 0, stream>>>(
            node_feat, node_deg, net_cnt, csr,
            W1, b1, Zb, C, pin_feat, out_net, out_node);
    }
}

// Round 14
// 195.460 us; speedup vs baseline: 1.5570x; 1.5570x over previous
//
#include <hip/hip_runtime.h>
#include <hip/hip_bf16.h>

#define N_NODE 100000
#define N_NET  20000
#define NE     200000
#define H_NODE 64
#define H_NET  32
#define H_PIN  16
#define O_NODE 32
#define O_NET  64
#define CSR_STRIDE 64   // max net degree ~26 for this input (Binomial(2e5,1/2e4))

#define ZNPB 16

// ---------------- workspace layout (bytes, 16-aligned) ----------------
// zeroed by memset: [0, 480000)
//   node_deg : int  [N_NODE]          off 0          (400000)
//   net_cnt  : int  [N_NET]           off 400000     (80000)
// csr : int2  [N_NET*64]              off 480000     (10240000)
// Zb  : bf16  [N_NET*512] [n][o][k]   off 10720000   (20480000)
// C   : float [N_NET*32]              off 31200000   (2560000)

#define OFF_NETCNT  400000
#define OFF_CSR     480000
#define OFF_Z       10720000
#define OFF_C       31200000
#define ZERO_BYTES  480000

static __device__ __forceinline__ unsigned short f2bf(float f) {
    unsigned int u = __float_as_uint(f);
    u += 0x7fff + ((u >> 16) & 1);          // round-to-nearest-even
    return (unsigned short)(u >> 16);
}
static __device__ __forceinline__ float bf2f(unsigned short h) {
    return __uint_as_float(((unsigned int)h) << 16);
}

// mixed grid: [0,782) edge deg+csr | [782,2032) Z/C | [2032,5157) out_node:=b_nn
#define BLD_EDGE_BLKS 782
#define BLD_Z_BLKS    1250
#define BLD_INIT_BLKS 3125

__global__ void k_build(const int* __restrict__ en, const int* __restrict__ em,
                        int* __restrict__ node_deg, int* __restrict__ net_cnt,
                        int2* __restrict__ csr,
                        const float* __restrict__ net_feat,
                        const float* __restrict__ W2, const float* __restrict__ b2,
                        unsigned short* __restrict__ Zb, float* __restrict__ C,
                        const float* __restrict__ b_nn,
                        float* __restrict__ out_node) {
    int t = threadIdx.x, b = blockIdx.x;
    if (b < BLD_EDGE_BLKS) {
        int e = b * 256 + t;
        if (e < NE) {
            int v = en[e], n = em[e];
            atomicAdd(&node_deg[v], 1);
            int slot = atomicAdd(&net_cnt[n], 1);
            if (slot < CSR_STRIDE) csr[n * CSR_STRIDE + slot] = make_int2(e, v);
        }
        return;
    }
    if (b < BLD_EDGE_BLKS + BLD_Z_BLKS) {
        __shared__ float sy[ZNPB][H_NET];
        int base = (b - BLD_EDGE_BLKS) * ZNPB;
        for (int idx = t; idx < ZNPB * H_NET; idx += 256)
            sy[idx >> 5][idx & 31] = net_feat[(base + (idx >> 5)) * H_NET + (idx & 31)];
        __syncthreads();
        int o = t & 31, k4 = (t >> 5) & 3, rep = t >> 7;   // 8 nets per thread
        const float* w2p = W2 + (k4 * 4) * 1024 + o;
        float4 acc[8];
#pragma unroll
        for (int g = 0; g < 8; g++) acc[g] = make_float4(0.f, 0.f, 0.f, 0.f);
#pragma unroll 4
        for (int i = 0; i < H_NET; i++) {
            float w0 = w2p[0 * 1024 + i * 32];
            float w1 = w2p[1 * 1024 + i * 32];
            float w2v = w2p[2 * 1024 + i * 32];
            float w3 = w2p[3 * 1024 + i * 32];
#pragma unroll
            for (int g = 0; g < 8; g++) {
                float y = sy[rep * 8 + g][i];
                acc[g].x += w0 * y; acc[g].y += w1 * y;
                acc[g].z += w2v * y; acc[g].w += w3 * y;
            }
        }
#pragma unroll
        for (int g = 0; g < 8; g++) {
            int n = base + rep * 8 + g;
            ushort4 uz;
            uz.x = f2bf(acc[g].x); uz.y = f2bf(acc[g].y);
            uz.z = f2bf(acc[g].z); uz.w = f2bf(acc[g].w);
            *(ushort4*)&Zb[(size_t)n * 512 + o * 16 + k4 * 4] = uz;
        }
#pragma unroll
        for (int r = 0; r < 2; r++) {
            int idx = t + r * 256;
            int g = idx >> 5, oo = idx & 31;
            float a = 0.f;
#pragma unroll
            for (int i = 0; i < H_NET; i++) a += sy[g][i] * b2[i * 32 + oo];
            C[(base + g) * 32 + oo] = a;
        }
        return;
    }
    int idx = (b - BLD_EDGE_BLKS - BLD_Z_BLKS) * 256 + t;   // < 800000 float4s
    ((float4*)out_node)[idx] = ((const float4*)b_nn)[idx & 7];
}

// per-net fused kernel: 4 nets/block, one wave each. Chunk = 32 edges.
// RULE (gfx950): every __shfl must execute as an UNCONDITIONAL statement with
// the full wave converged — never inside a ternary/if with a LANE-VARYING
// condition. Wave-uniform branches (on cnt/deg) are fine. Select on results.
// Structure per chunk: csr load (drain) -> ALL shfl index collection ->
// issue node loads + pin loads together (one merged drain) -> node fma ->
// LDS pin write -> messages (LDS + regs only).
__global__ void k_net(const float* __restrict__ node_feat,
                      const int* __restrict__ node_deg,
                      const int* __restrict__ net_cnt,
                      const int2* __restrict__ csr,
                      const float* __restrict__ W1, const float* __restrict__ b1,
                      const unsigned short* __restrict__ Zb,
                      const float* __restrict__ Cg,
                      const float* __restrict__ pin_feat,
                      float* __restrict__ out_net, float* __restrict__ out_node) {
    __shared__ float  spin[4][32][16];   // 8 KB
    __shared__ float4 srow4[4][16];      // 1 KB
    int t = threadIdx.x;
    int w = t >> 6, l = t & 63;
    int n = blockIdx.x * 4 + w;          // 5000 blocks exactly
    int beg = n * CSR_STRIDE, deg = net_cnt[n];
    int o = l & 31, half = l >> 5, q = l >> 4, f = l & 15;

    // Z row: 32B of bf16 per lane, unpack to 16 fp32 regs
    float z[16];
    {
        const uint4* zp = (const uint4*)&Zb[(size_t)n * 512 + o * 16];
        uint4 za = zp[0], zb = zp[1];
        unsigned int uu[8] = {za.x, za.y, za.z, za.w, zb.x, zb.y, zb.z, zb.w};
#pragma unroll
        for (int i = 0; i < 8; i++) {
            z[2 * i]     = bf2f((unsigned short)(uu[i] & 0xffffu));
            z[2 * i + 1] = bf2f((unsigned short)(uu[i] >> 16));
        }
    }
    float c = Cg[n * 32 + o];
    const float4* nf4 = (const float4*)node_feat;
    const float4* pf4 = (const float4*)pin_feat;
    float4 acc4 = make_float4(0.f, 0.f, 0.f, 0.f);

    for (int j0 = 0; j0 < deg; j0 += 32) {
        int cnt = deg - j0; if (cnt > 32) cnt = 32;    // wave-uniform
        int vj = 0, ej = 0; float sj = 0.f;
        if (l < cnt) {
            int2 ev = csr[beg + j0 + l];
            ej = ev.x; vj = ev.y;
            // node_deg[vj] >= 1 by construction (vj appears in edge list)
            sj = rsqrtf((float)node_deg[vj]);
        }
        bool two = (cnt > 16);                          // wave-uniform

        // ---- collect ALL indices up front (converged shfls) ----
        int pe0, pe1 = 0;                               // pin-staging edge ids
        {
            int jj = l >> 2;
            int src = (jj < cnt) ? jj : cnt - 1;
            pe0 = __shfl(ej, src);
        }
        if (two) {
            int jj = 16 + (l >> 2);
            int src = (jj < cnt) ? jj : cnt - 1;
            pe1 = __shfl(ej, src);
        }
        int vv[8]; float ss[8];
        int nbat = two ? 8 : 4;                         // wave-uniform
#pragma unroll
        for (int r = 0; r < 4; r++) {
            int jj = r * 4 + q;
            int src = (jj < cnt) ? jj : cnt - 1;
            vv[r] = __shfl(vj, src);
            float sv = __shfl(sj, src);
            ss[r] = (jj < cnt) ? sv : 0.f;
        }
        if (two) {
#pragma unroll
            for (int r = 4; r < 8; r++) {
                int jj = 16 + (r - 4) * 4 + q;
                int src = (jj < cnt) ? jj : cnt - 1;
                vv[r] = __shfl(vj, src);
                float sv = __shfl(sj, src);
                ss[r] = (jj < cnt) ? sv : 0.f;
            }
        }

        // ---- issue ALL global loads together (node rows + pin rows) ----
        float4 xx[8];
#pragma unroll
        for (int r = 0; r < 4; r++) xx[r] = nf4[(size_t)vv[r] * 16 + f];
        if (two) {
#pragma unroll
            for (int r = 4; r < 8; r++) xx[r] = nf4[(size_t)vv[r] * 16 + f];
        }
        float4 pv0 = pf4[(size_t)pe0 * 4 + (l & 3)];
        float4 pv1 = make_float4(0.f, 0.f, 0.f, 0.f);
        if (two) pv1 = pf4[(size_t)pe1 * 4 + (l & 3)];

        // ---- node fma (drains node loads; pin loads may still be in flight) ----
        for (int r = 0; r < nbat; r++) {
            acc4.x += xx[r].x * ss[r]; acc4.y += xx[r].y * ss[r];
            acc4.z += xx[r].z * ss[r]; acc4.w += xx[r].w * ss[r];
        }

        // ---- stage pins to LDS ----
        ((float4*)&spin[w][l >> 2][0])[l & 3] = pv0;
        if (two) ((float4*)&spin[w][16 + (l >> 2)][0])[l & 3] = pv1;

        // ---- messages: half-wave per edge; pins LDS; z regs; direct scatter ----
        for (int jj = 0; jj < cnt; jj += 2) {
            int je = jj + half;
            int src = (je < cnt) ? je : cnt - 1;
            int v = __shfl(vj, src);
            float sv = __shfl(sj, src);
            float inv = sv * sv;                        // 1/deg_v
            const float4* pr = (const float4*)&spin[w][src][0];
            float m = c;
#pragma unroll
            for (int k4 = 0; k4 < 4; k4++) {
                float4 pv = pr[k4];
                m += pv.x * z[k4 * 4 + 0] + pv.y * z[k4 * 4 + 1]
                   + pv.z * z[k4 * 4 + 2] + pv.w * z[k4 * 4 + 3];
            }
            if (je < cnt) atomicAdd(&out_node[(size_t)v * O_NODE + o], m * inv);
        }
    }
    // combine quarters (wave-internal butterflies)
    acc4.x += __shfl_xor(acc4.x, 16); acc4.y += __shfl_xor(acc4.y, 16);
    acc4.z += __shfl_xor(acc4.z, 16); acc4.w += __shfl_xor(acc4.w, 16);
    acc4.x += __shfl_xor(acc4.x, 32); acc4.y += __shfl_xor(acc4.y, 32);
    acc4.z += __shfl_xor(acc4.z, 32); acc4.w += __shfl_xor(acc4.w, 32);
    float dn = (deg < 1) ? 1.f : (float)deg;
    float rs = rsqrtf(dn);
    if (l < 16)
        srow4[w][l] = make_float4(acc4.x * rs, acc4.y * rs, acc4.z * rs, acc4.w * rs);
    // srow4[w]/spin[w] are same-wave LDS: no __syncthreads needed
    {
        const float* a = (const float*)&srow4[w][0];
        float oacc = b1[l];
#pragma unroll 16
        for (int h = 0; h < H_NODE; h++) oacc += a[h] * W1[h * O_NET + l];
        out_net[n * O_NET + l] = oacc;
    }
}

extern "C" void kernel_launch(void* const* d_in, const int* in_sizes, int n_in,
                              void* d_out, int out_size, void* d_ws, size_t ws_size,
                              hipStream_t stream) {
    const float* node_feat = (const float*)d_in[0];
    const float* net_feat  = (const float*)d_in[1];
    const float* pin_feat  = (const float*)d_in[2];
    const int*   edge_node = (const int*)d_in[3];
    const int*   edge_net  = (const int*)d_in[4];
    const float* W1        = (const float*)d_in[5];
    const float* b1        = (const float*)d_in[6];
    const float* W2        = (const float*)d_in[7];
    const float* b2        = (const float*)d_in[8];
    const float* b_nn      = (const float*)d_in[9];

    float* out_node = (float*)d_out;                          // [N_NODE*32]
    float* out_net  = out_node + (size_t)N_NODE * O_NODE;     // [N_NET*64]

    char* ws = (char*)d_ws;
    int*            node_deg = (int*)ws;
    int*            net_cnt  = (int*)(ws + OFF_NETCNT);
    int2*           csr      = (int2*)(ws + OFF_CSR);
    unsigned short* Zb       = (unsigned short*)(ws + OFF_Z);
    float*          C        = (float*)(ws + OFF_C);

    (void)hipMemsetAsync(ws, 0, ZERO_BYTES, stream);

    k_build<<<BLD_EDGE_BLKS + BLD_Z_BLKS + BLD_INIT_BLKS, 256, 0, stream>>>(
        edge_node, edge_net, node_deg, net_cnt, csr,
        net_feat, W2, b2, Zb, C, b_nn, out_node);

    k_net<<<N_NET / 4, 256, 0, stream>>>(
        node_feat, node_deg, net_cnt, csr,
        W1, b1, Zb, C, pin_feat, out_net, out_node);
}

// Round 15
// 164.508 us; speedup vs baseline: 1.8499x; 1.1881x over previous
//
#include <hip/hip_runtime.h>
#include <hip/hip_bf16.h>

#define N_NODE 100000
#define N_NET  20000
#define NE     200000
#define H_NODE 64
#define H_NET  32
#define H_PIN  16
#define O_NODE 32
#define O_NET  64
#define CSR_STRIDE 64   // max net degree ~26 for this input (Binomial(2e5,1/2e4))

#define ZNPB 16

// ---------------- workspace layout (bytes, 16-aligned) ----------------
// zeroed by memset: [0, 480000)
//   node_deg : int  [N_NODE]          off 0          (400000)
//   net_cnt  : int  [N_NET]           off 400000     (80000)
// csr : int2  [N_NET*64]              off 480000     (10240000)
// Zb  : bf16  [N_NET*512] [n][o][k]   off 10720000   (20480000)
// C   : float [N_NET*32]              off 31200000   (2560000)

#define OFF_NETCNT  400000
#define OFF_CSR     480000
#define OFF_Z       10720000
#define OFF_C       31200000
#define ZERO_BYTES  480000

static __device__ __forceinline__ unsigned short f2bf(float f) {
    unsigned int u = __float_as_uint(f);
    u += 0x7fff + ((u >> 16) & 1);          // round-to-nearest-even
    return (unsigned short)(u >> 16);
}
static __device__ __forceinline__ float bf2f(unsigned short h) {
    return __uint_as_float(((unsigned int)h) << 16);
}

// mixed grid: [0,782) edge deg+csr | [782,2032) Z/C | [2032,5157) out_node:=b_nn
#define BLD_EDGE_BLKS 782
#define BLD_Z_BLKS    1250
#define BLD_INIT_BLKS 3125

__global__ void k_build(const int* __restrict__ en, const int* __restrict__ em,
                        int* __restrict__ node_deg, int* __restrict__ net_cnt,
                        int2* __restrict__ csr,
                        const float* __restrict__ net_feat,
                        const float* __restrict__ W2, const float* __restrict__ b2,
                        unsigned short* __restrict__ Zb, float* __restrict__ C,
                        const float* __restrict__ b_nn,
                        float* __restrict__ out_node) {
    int t = threadIdx.x, b = blockIdx.x;
    if (b < BLD_EDGE_BLKS) {
        int e = b * 256 + t;
        if (e < NE) {
            int v = en[e], n = em[e];
            atomicAdd(&node_deg[v], 1);
            int slot = atomicAdd(&net_cnt[n], 1);
            if (slot < CSR_STRIDE) csr[n * CSR_STRIDE + slot] = make_int2(e, v);
        }
        return;
    }
    if (b < BLD_EDGE_BLKS + BLD_Z_BLKS) {
        __shared__ float sy[ZNPB][H_NET];
        int base = (b - BLD_EDGE_BLKS) * ZNPB;
        for (int idx = t; idx < ZNPB * H_NET; idx += 256)
            sy[idx >> 5][idx & 31] = net_feat[(base + (idx >> 5)) * H_NET + (idx & 31)];
        __syncthreads();
        int o = t & 31, k4 = (t >> 5) & 3, rep = t >> 7;   // 8 nets per thread
        const float* w2p = W2 + (k4 * 4) * 1024 + o;
        float4 acc[8];
#pragma unroll
        for (int g = 0; g < 8; g++) acc[g] = make_float4(0.f, 0.f, 0.f, 0.f);
#pragma unroll 4
        for (int i = 0; i < H_NET; i++) {
            float w0 = w2p[0 * 1024 + i * 32];
            float w1 = w2p[1 * 1024 + i * 32];
            float w2v = w2p[2 * 1024 + i * 32];
            float w3 = w2p[3 * 1024 + i * 32];
#pragma unroll
            for (int g = 0; g < 8; g++) {
                float y = sy[rep * 8 + g][i];
                acc[g].x += w0 * y; acc[g].y += w1 * y;
                acc[g].z += w2v * y; acc[g].w += w3 * y;
            }
        }
#pragma unroll
        for (int g = 0; g < 8; g++) {
            int n = base + rep * 8 + g;
            ushort4 uz;
            uz.x = f2bf(acc[g].x); uz.y = f2bf(acc[g].y);
            uz.z = f2bf(acc[g].z); uz.w = f2bf(acc[g].w);
            *(ushort4*)&Zb[(size_t)n * 512 + o * 16 + k4 * 4] = uz;
        }
#pragma unroll
        for (int r = 0; r < 2; r++) {
            int idx = t + r * 256;
            int g = idx >> 5, oo = idx & 31;
            float a = 0.f;
#pragma unroll
            for (int i = 0; i < H_NET; i++) a += sy[g][i] * b2[i * 32 + oo];
            C[(base + g) * 32 + oo] = a;
        }
        return;
    }
    int idx = (b - BLD_EDGE_BLKS - BLD_Z_BLKS) * 256 + t;   // < 800000 float4s
    ((float4*)out_node)[idx] = ((const float4*)b_nn)[idx & 7];
}

// per-net fused kernel: 4 nets/block, one wave each. Chunk = 32 edges.
// RULE (gfx950): every __shfl must execute as an UNCONDITIONAL statement with
// the full wave converged — never inside a ternary/if with a LANE-VARYING
// condition. Wave-uniform branches (on cnt/deg) are fine. Select on results.
// RULE (compiler): NO runtime-bounded loop may index a per-lane array —
// dynamic indexing forces scratch spill (round 14: +82MB WRITE, 2x slower).
// All per-lane arrays live in fully-unrolled, compile-time-bounded scopes.
__global__ void k_net(const float* __restrict__ node_feat,
                      const int* __restrict__ node_deg,
                      const int* __restrict__ net_cnt,
                      const int2* __restrict__ csr,
                      const float* __restrict__ W1, const float* __restrict__ b1,
                      const unsigned short* __restrict__ Zb,
                      const float* __restrict__ Cg,
                      const float* __restrict__ pin_feat,
                      float* __restrict__ out_net, float* __restrict__ out_node) {
    __shared__ float  spin[4][32][16];   // 8 KB
    __shared__ float4 srow4[4][16];      // 1 KB
    int t = threadIdx.x;
    int w = t >> 6, l = t & 63;
    int n = blockIdx.x * 4 + w;          // 5000 blocks exactly
    int beg = n * CSR_STRIDE, deg = net_cnt[n];
    int o = l & 31, half = l >> 5, q = l >> 4, f = l & 15;

    // Z row: 32B of bf16 per lane, unpack to 16 fp32 regs
    float z[16];
    {
        const uint4* zp = (const uint4*)&Zb[(size_t)n * 512 + o * 16];
        uint4 za = zp[0], zb = zp[1];
        unsigned int uu[8] = {za.x, za.y, za.z, za.w, zb.x, zb.y, zb.z, zb.w};
#pragma unroll
        for (int i = 0; i < 8; i++) {
            z[2 * i]     = bf2f((unsigned short)(uu[i] & 0xffffu));
            z[2 * i + 1] = bf2f((unsigned short)(uu[i] >> 16));
        }
    }
    float c = Cg[n * 32 + o];
    const float4* nf4 = (const float4*)node_feat;
    const float4* pf4 = (const float4*)pin_feat;
    float4 acc4 = make_float4(0.f, 0.f, 0.f, 0.f);

    for (int j0 = 0; j0 < deg; j0 += 32) {
        int cnt = deg - j0; if (cnt > 32) cnt = 32;    // wave-uniform
        int vj = 0, ej = 0; float sj = 0.f;
        if (l < cnt) {
            int2 ev = csr[beg + j0 + l];
            ej = ev.x; vj = ev.y;
            sj = rsqrtf((float)node_deg[vj]);  // node_deg>=1 by construction
        }
        bool two = (cnt > 16);                          // wave-uniform
        int jp0 = l >> 2;
        int sp0 = (jp0 < cnt) ? jp0 : cnt - 1;
        int pe0 = __shfl(ej, sp0);                      // converged

        if (two) {
            // ---- batch A+B: collect, issue ALL loads, then consume ----
            int vvA[4]; float ssA[4];
#pragma unroll
            for (int r = 0; r < 4; r++) {
                int jj = r * 4 + q;
                int src = (jj < cnt) ? jj : cnt - 1;
                vvA[r] = __shfl(vj, src);
                float sv = __shfl(sj, src);
                ssA[r] = (jj < cnt) ? sv : 0.f;
            }
            int vvB[4]; float ssB[4];
#pragma unroll
            for (int r = 0; r < 4; r++) {
                int jj = 16 + r * 4 + q;
                int src = (jj < cnt) ? jj : cnt - 1;
                vvB[r] = __shfl(vj, src);
                float sv = __shfl(sj, src);
                ssB[r] = (jj < cnt) ? sv : 0.f;
            }
            int jp1 = 16 + (l >> 2);
            int sp1 = (jp1 < cnt) ? jp1 : cnt - 1;
            int pe1 = __shfl(ej, sp1);                  // converged
            float4 xxA[4], xxB[4];
#pragma unroll
            for (int r = 0; r < 4; r++) xxA[r] = nf4[(size_t)vvA[r] * 16 + f];
#pragma unroll
            for (int r = 0; r < 4; r++) xxB[r] = nf4[(size_t)vvB[r] * 16 + f];
            float4 pv0 = pf4[(size_t)pe0 * 4 + (l & 3)];
            float4 pv1 = pf4[(size_t)pe1 * 4 + (l & 3)];
#pragma unroll
            for (int r = 0; r < 4; r++) {
                acc4.x += xxA[r].x * ssA[r]; acc4.y += xxA[r].y * ssA[r];
                acc4.z += xxA[r].z * ssA[r]; acc4.w += xxA[r].w * ssA[r];
            }
#pragma unroll
            for (int r = 0; r < 4; r++) {
                acc4.x += xxB[r].x * ssB[r]; acc4.y += xxB[r].y * ssB[r];
                acc4.z += xxB[r].z * ssB[r]; acc4.w += xxB[r].w * ssB[r];
            }
            ((float4*)&spin[w][jp0][0])[l & 3] = pv0;
            ((float4*)&spin[w][jp1][0])[l & 3] = pv1;
        } else {
            int vvA[4]; float ssA[4];
#pragma unroll
            for (int r = 0; r < 4; r++) {
                int jj = r * 4 + q;
                int src = (jj < cnt) ? jj : cnt - 1;
                vvA[r] = __shfl(vj, src);
                float sv = __shfl(sj, src);
                ssA[r] = (jj < cnt) ? sv : 0.f;
            }
            float4 xxA[4];
#pragma unroll
            for (int r = 0; r < 4; r++) xxA[r] = nf4[(size_t)vvA[r] * 16 + f];
            float4 pv0 = pf4[(size_t)pe0 * 4 + (l & 3)];
#pragma unroll
            for (int r = 0; r < 4; r++) {
                acc4.x += xxA[r].x * ssA[r]; acc4.y += xxA[r].y * ssA[r];
                acc4.z += xxA[r].z * ssA[r]; acc4.w += xxA[r].w * ssA[r];
            }
            ((float4*)&spin[w][jp0][0])[l & 3] = pv0;
        }

        // ---- messages: half-wave per edge; pins LDS; z regs; direct scatter ----
        for (int jj = 0; jj < cnt; jj += 2) {
            int je = jj + half;
            int src = (je < cnt) ? je : cnt - 1;
            int v = __shfl(vj, src);
            float sv = __shfl(sj, src);
            float inv = sv * sv;                        // 1/deg_v
            const float4* pr = (const float4*)&spin[w][src][0];
            float m = c;
#pragma unroll
            for (int k4 = 0; k4 < 4; k4++) {
                float4 pv = pr[k4];
                m += pv.x * z[k4 * 4 + 0] + pv.y * z[k4 * 4 + 1]
                   + pv.z * z[k4 * 4 + 2] + pv.w * z[k4 * 4 + 3];
            }
            if (je < cnt) atomicAdd(&out_node[(size_t)v * O_NODE + o], m * inv);
        }
    }
    // combine quarters (wave-internal butterflies)
    acc4.x += __shfl_xor(acc4.x, 16); acc4.y += __shfl_xor(acc4.y, 16);
    acc4.z += __shfl_xor(acc4.z, 16); acc4.w += __shfl_xor(acc4.w, 16);
    acc4.x += __shfl_xor(acc4.x, 32); acc4.y += __shfl_xor(acc4.y, 32);
    acc4.z += __shfl_xor(acc4.z, 32); acc4.w += __shfl_xor(acc4.w, 32);
    float dn = (deg < 1) ? 1.f : (float)deg;
    float rs = rsqrtf(dn);
    if (l < 16)
        srow4[w][l] = make_float4(acc4.x * rs, acc4.y * rs, acc4.z * rs, acc4.w * rs);
    // srow4[w]/spin[w] are same-wave LDS: no __syncthreads needed
    {
        const float* a = (const float*)&srow4[w][0];
        float oacc = b1[l];
#pragma unroll 16
        for (int h = 0; h < H_NODE; h++) oacc += a[h] * W1[h * O_NET + l];
        out_net[n * O_NET + l] = oacc;
    }
}

extern "C" void kernel_launch(void* const* d_in, const int* in_sizes, int n_in,
                              void* d_out, int out_size, void* d_ws, size_t ws_size,
                              hipStream_t stream) {
    const float* node_feat = (const float*)d_in[0];
    const float* net_feat  = (const float*)d_in[1];
    const float* pin_feat  = (const float*)d_in[2];
    const int*   edge_node = (const int*)d_in[3];
    const int*   edge_net  = (const int*)d_in[4];
    const float* W1        = (const float*)d_in[5];
    const float* b1        = (const float*)d_in[6];
    const float* W2        = (const float*)d_in[7];
    const float* b2        = (const float*)d_in[8];
    const float* b_nn      = (const float*)d_in[9];

    float* out_node = (float*)d_out;                          // [N_NODE*32]
    float* out_net  = out_node + (size_t)N_NODE * O_NODE;     // [N_NET*64]

    char* ws = (char*)d_ws;
    int*            node_deg = (int*)ws;
    int*            net_cnt  = (int*)(ws + OFF_NETCNT);
    int2*           csr      = (int2*)(ws + OFF_CSR);
    unsigned short* Zb       = (unsigned short*)(ws + OFF_Z);
    float*          C        = (float*)(ws + OFF_C);

    (void)hipMemsetAsync(ws, 0, ZERO_BYTES, stream);

    k_build<<<BLD_EDGE_BLKS + BLD_Z_BLKS + BLD_INIT_BLKS, 256, 0, stream>>>(
        edge_node, edge_net, node_deg, net_cnt, csr,
        net_feat, W2, b2, Zb, C, b_nn, out_node);

    k_net<<<N_NET / 4, 256, 0, stream>>>(
        node_feat, node_deg, net_cnt, csr,
        W1, b1, Zb, C, pin_feat, out_net, out_node);
}